// Round 4
// baseline (183.082 us; speedup 1.0000x reference)
//
#include <hip/hip_runtime.h>

// x shape (8,32,256,256) float32 holding exact integers 0..255; K=3, stride 1, no pad.
#define B_   8
#define C_   32
#define H_   256
#define W_   256
#define BC_  (B_ * C_)
#define HO_  (H_ - 2)           // 254
#define WO_  (W_ - 2)           // 254
#define NIN_  (BC_ * H_ * W_)   // 16,777,216
#define NBINS 256
#define HCOLS 16                // sub-histogram columns (bank-aliasing <=2-way avg)
#define HIST_BLOCKS 2048        // NIN_/4 = HIST_BLOCKS*256*8 exactly

// Module-owned global histogram (d_ws proved unsafe in R1). 8-aligned for packed
// 64-bit atomics in the reduction. Re-zeroed every call.
__device__ __align__(8) int g_hist[NBINS];

__global__ void zero_hist_kernel() { g_hist[threadIdx.x] = 0; }

// R3 post-mortem: v2 was latency-bound (VALUBusy 3.4%, HBM 9%) — only 2 loads in
// flight per wave. v3: 8 independent float4 loads (128 B/thread) issued before any
// atomic; compiler consumes with progressive vmcnt waits. Column sub-histograms
// sh[bin*16 + (t&15)] keep LDS-atomic aliasing ~2-way (free).
__global__ __launch_bounds__(256, 4) void hist_kernel(const float* __restrict__ x) {
    __shared__ int sh[NBINS * HCOLS];   // 16 KB
    const int t = threadIdx.x;
    for (int i = t; i < NBINS * HCOLS; i += 256) sh[i] = 0;
    __syncthreads();

    const int col = t & (HCOLS - 1);
    const float4* x4 = (const float4*)x;
    const int gt = blockIdx.x * 256 + t;     // 0 .. 524287
    const int stride = HIST_BLOCKS * 256;    // 524288 float4s apart

    float4 v[8];
#pragma unroll
    for (int k = 0; k < 8; ++k) v[k] = x4[gt + k * stride];
#pragma unroll
    for (int k = 0; k < 8; ++k) {
        atomicAdd(&sh[((int)v[k].x) * HCOLS + col], 1);
        atomicAdd(&sh[((int)v[k].y) * HCOLS + col], 1);
        atomicAdd(&sh[((int)v[k].z) * HCOLS + col], 1);
        atomicAdd(&sh[((int)v[k].w) * HCOLS + col], 1);
    }
    __syncthreads();

    // Rotated-index column reduction (conflict-light), pair-packed 64-bit global atomic.
    if (t < 128) {
        const int b0 = 2 * t, b1 = 2 * t + 1;
        int s0 = 0, s1 = 0;
#pragma unroll
        for (int c = 0; c < HCOLS; ++c) {
            const int cc = (c + t) & (HCOLS - 1);
            s0 += sh[b0 * HCOLS + cc];
            s1 += sh[b1 * HCOLS + cc];
        }
        unsigned long long packed =
            (unsigned long long)(unsigned int)s0 | ((unsigned long long)(unsigned int)s1 << 32);
        atomicAdd((unsigned long long*)&g_hist[b0], packed);
    }
}

// Block = one (bc, 16-output-row strip). Load 18x256 input tile once, ONE key-table
// lookup per input element (key = (count<<8)|value precomputed per bin), store key
// in LDS. Compute reads keys stride-1 (2-way bank alias = free) with 3-register row
// rotation: 3 new LDS reads per output. Argmin on (key & ~255) strict '<' == exact
// positional first-min (row-major di,dj — matches jnp.argmin). counts <= ~66k so
// count<<8 fits int32 comfortably.
__global__ __launch_bounds__(256) void pool_kernel(const float* __restrict__ x,
                                                   float* __restrict__ out) {
    __shared__ int key_s[NBINS];
    __shared__ int tile[18 * W_];   // 18 KB
    const int t = threadIdx.x;
    key_s[t] = (g_hist[t] << 8) | t;
    __syncthreads();

    const int bc = blockIdx.x >> 4;
    const int s  = blockIdx.x & 15;
    const int r0 = s * 16;
    const int rows_out = (r0 + 16 <= HO_) ? 16 : (HO_ - r0);  // 16, last strip 14
    const int rows_in  = rows_out + 2;                        // 18 / 16 (fits H_)

    const float4* xin = (const float4*)(x + ((long long)bc * H_ + r0) * W_);
    const int nf4 = rows_in * (W_ / 4);
    for (int idx = t; idx < nf4; idx += 256) {
        float4 v = xin[idx];
        int4 k;
        k.x = key_s[(int)v.x];
        k.y = key_s[(int)v.y];
        k.z = key_s[(int)v.z];
        k.w = key_s[(int)v.w];
        ((int4*)tile)[idx] = k;
    }
    __syncthreads();

    if (t >= WO_) return;   // no further barriers below

    int a0 = tile[t],        a1 = tile[t + 1],        a2 = tile[t + 2];
    int b0 = tile[W_ + t],   b1 = tile[W_ + t + 1],   b2 = tile[W_ + t + 2];
    float* orow = out + ((long long)bc * HO_ + r0) * WO_ + t;
    for (int r = 0; r < rows_out; ++r) {
        const int base = (r + 2) * W_ + t;
        const int c0 = tile[base], c1 = tile[base + 1], c2 = tile[base + 2];
        int best = a0, bm = a0 & ~255;
#define CAND(kk) { const int m = (kk) & ~255; if (m < bm) { bm = m; best = (kk); } }
        CAND(a1) CAND(a2) CAND(b0) CAND(b1) CAND(b2) CAND(c0) CAND(c1) CAND(c2)
#undef CAND
        orow[(long long)r * WO_] = (float)(best & 255);
        a0 = b0; a1 = b1; a2 = b2;
        b0 = c0; b1 = c1; b2 = c2;
    }
}

extern "C" void kernel_launch(void* const* d_in, const int* in_sizes, int n_in,
                              void* d_out, int out_size, void* d_ws, size_t ws_size,
                              hipStream_t stream) {
    const float* x = (const float*)d_in[0];
    float* out = (float*)d_out;
    (void)d_ws; (void)ws_size;

    zero_hist_kernel<<<1, NBINS, 0, stream>>>();
    hist_kernel<<<HIST_BLOCKS, 256, 0, stream>>>(x);
    pool_kernel<<<BC_ * 16, 256, 0, stream>>>(x, out);
}

// Round 5
// 132.811 us; speedup vs baseline: 1.3785x; 1.3785x over previous
//
#include <hip/hip_runtime.h>

// x shape (8,32,256,256) float32 holding exact integers 0..255; K=3, stride 1, no pad.
#define B_   8
#define C_   32
#define H_   256
#define W_   256
#define BC_  (B_ * C_)
#define HO_  (H_ - 2)           // 254
#define WO_  (W_ - 2)           // 254
#define NIN_  (BC_ * H_ * W_)   // 16,777,216
#define NBINS 256
#define HCOLS 16                // sub-histogram columns (LDS-atomic aliasing ~2-way = free)
#define HBLOCKS 1024            // NIN_/4 = HBLOCKS*256*16 exactly

// R4 post-mortem: device-scope atomic fan-in (262144 packed atomics -> 128 addrs)
// was the entire cost of hist (WRITE_SIZE 2176 KB = one fabric txn per atomic,
// ~35 ns/txn serialized per address = ~70 us). v4: per-block partial histograms
// written with PLAIN coalesced stores; tiny reduce kernel does 8 atomics/addr.
__device__ __align__(8) int g_hist[NBINS];
__device__ int g_part[HBLOCKS * NBINS];   // 1 MB, fully overwritten each call

__global__ void zero_hist_kernel() { g_hist[threadIdx.x] = 0; }

__global__ __launch_bounds__(256) void hist_kernel(const float* __restrict__ x) {
    __shared__ int sh[NBINS * HCOLS];   // 16 KB
    const int t = threadIdx.x;
    for (int i = t; i < NBINS * HCOLS; i += 256) sh[i] = 0;
    __syncthreads();

    const int col = t & (HCOLS - 1);
    const float4* x4 = (const float4*)x;
    const int stride = HBLOCKS * 256;          // 262144 float4s
    float4 v[8];
#pragma unroll
    for (int half = 0; half < 2; ++half) {
        const int base = blockIdx.x * 256 + t + half * 8 * stride;
#pragma unroll
        for (int k = 0; k < 8; ++k) v[k] = x4[base + k * stride];  // 8 loads in flight
#pragma unroll
        for (int k = 0; k < 8; ++k) {
            atomicAdd(&sh[((int)v[k].x) * HCOLS + col], 1);
            atomicAdd(&sh[((int)v[k].y) * HCOLS + col], 1);
            atomicAdd(&sh[((int)v[k].z) * HCOLS + col], 1);
            atomicAdd(&sh[((int)v[k].w) * HCOLS + col], 1);
        }
    }
    __syncthreads();

    // Per-bin column sum, rotated so bank = (17t+c) mod 32 (2-way = free); plain store.
    int s0 = 0;
#pragma unroll
    for (int c = 0; c < HCOLS; ++c) {
        const int cc = (c + t) & (HCOLS - 1);
        s0 += sh[t * HCOLS + cc];
    }
    g_part[blockIdx.x * NBINS + t] = s0;
}

// 8 blocks x 256 threads: block j sums partial rows [j*128, j*128+128) (coalesced,
// unroll-8 MLP), then ONE atomicAdd per thread -> 8 atomics per address total.
__global__ __launch_bounds__(256) void reduce_kernel() {
    const int t = threadIdx.x;
    const int r0 = blockIdx.x * (HBLOCKS / 8);
    int s = 0;
#pragma unroll 8
    for (int i = 0; i < HBLOCKS / 8; ++i) s += g_part[(r0 + i) * NBINS + t];
    atomicAdd(&g_hist[t], s);
}

// Block = one (bc, 16-output-row strip). Load 18x256 input tile once, ONE key-table
// lookup per input element (key = (count<<8)|value precomputed per bin), store key
// in LDS. Compute reads keys stride-1 (2-way bank alias = free) with 3-register row
// rotation: 3 new LDS reads per output. Argmin on (key & ~255) strict '<' == exact
// positional first-min (row-major di,dj — matches jnp.argmin).
__global__ __launch_bounds__(256) void pool_kernel(const float* __restrict__ x,
                                                   float* __restrict__ out) {
    __shared__ int key_s[NBINS];
    __shared__ int tile[18 * W_];   // 18 KB
    const int t = threadIdx.x;
    key_s[t] = (g_hist[t] << 8) | t;
    __syncthreads();

    const int bc = blockIdx.x >> 4;
    const int s  = blockIdx.x & 15;
    const int r0 = s * 16;
    const int rows_out = (r0 + 16 <= HO_) ? 16 : (HO_ - r0);  // 16, last strip 14
    const int rows_in  = rows_out + 2;                        // 18 / 16 (fits H_)

    const float4* xin = (const float4*)(x + ((long long)bc * H_ + r0) * W_);
    const int nf4 = rows_in * (W_ / 4);
    for (int idx = t; idx < nf4; idx += 256) {
        float4 v = xin[idx];
        int4 k;
        k.x = key_s[(int)v.x];
        k.y = key_s[(int)v.y];
        k.z = key_s[(int)v.z];
        k.w = key_s[(int)v.w];
        ((int4*)tile)[idx] = k;
    }
    __syncthreads();

    if (t >= WO_) return;   // no further barriers below

    int a0 = tile[t],        a1 = tile[t + 1],        a2 = tile[t + 2];
    int b0 = tile[W_ + t],   b1 = tile[W_ + t + 1],   b2 = tile[W_ + t + 2];
    float* orow = out + ((long long)bc * HO_ + r0) * WO_ + t;
    for (int r = 0; r < rows_out; ++r) {
        const int base = (r + 2) * W_ + t;
        const int c0 = tile[base], c1 = tile[base + 1], c2 = tile[base + 2];
        int best = a0, bm = a0 & ~255;
#define CAND(kk) { const int m = (kk) & ~255; if (m < bm) { bm = m; best = (kk); } }
        CAND(a1) CAND(a2) CAND(b0) CAND(b1) CAND(b2) CAND(c0) CAND(c1) CAND(c2)
#undef CAND
        orow[(long long)r * WO_] = (float)(best & 255);
        a0 = b0; a1 = b1; a2 = b2;
        b0 = c0; b1 = c1; b2 = c2;
    }
}

extern "C" void kernel_launch(void* const* d_in, const int* in_sizes, int n_in,
                              void* d_out, int out_size, void* d_ws, size_t ws_size,
                              hipStream_t stream) {
    const float* x = (const float*)d_in[0];
    float* out = (float*)d_out;
    (void)d_ws; (void)ws_size;

    zero_hist_kernel<<<1, NBINS, 0, stream>>>();
    hist_kernel<<<HBLOCKS, 256, 0, stream>>>(x);
    reduce_kernel<<<8, 256, 0, stream>>>();
    pool_kernel<<<BC_ * 16, 256, 0, stream>>>(x, out);
}